// Round 5
// baseline (314.642 us; speedup 1.0000x reference)
//
#include <hip/hip_runtime.h>
#include <hip/hip_bf16.h>

#define DEV static __device__ __forceinline__

typedef __attribute__((ext_vector_type(4))) float f32x4;
typedef __attribute__((ext_vector_type(16))) float f32x16;
typedef __attribute__((ext_vector_type(8))) short short8;
typedef __attribute__((ext_vector_type(4))) unsigned short u16x4;
typedef __attribute__((ext_vector_type(4))) unsigned int u32x4;

#define NB 4
#define NT 2048
#define NDM 1024
#define NH 16
#define NDH 64
#define NM (NB * NT)  // 8192 rows

DEV float bf2f(unsigned short u) {
  union { unsigned int i; float f; } x;
  x.i = ((unsigned int)u) << 16;
  return x.f;
}
DEV unsigned short f2bf(float f) {
  __hip_bfloat16 h = __float2bfloat16(f);
  return *reinterpret_cast<unsigned short*>(&h);
}
DEV unsigned int pack2bf(float lo, float hi) {
  return ((unsigned int)f2bf(hi) << 16) | (unsigned int)f2bf(lo);
}
DEV short8 mkfrag(unsigned int w0, unsigned int w1, unsigned int w2, unsigned int w3) {
  union { u32x4 u; short8 s; } x;
  x.u[0] = w0; x.u[1] = w1; x.u[2] = w2; x.u[3] = w3;
  return x.s;
}
// exchange lane i <-> lane i^32 for both values (documented builtin: returns BOTH
// results, so the compiler materializes two distinct registers — the inline-asm
// "+v","+v" form let regalloc coalesce the copies into a self-swap -> R4 NaN).
DEV void permswap(unsigned int& a, unsigned int& b) {
  auto r = __builtin_amdgcn_permlane32_swap(a, b, false, false);
  a = r[0]; b = r[1];
}
DEV float xhalf_max(float v) {
  union { float f; unsigned int u; } x; x.f = v;
  unsigned int a = x.u, b = x.u;
  permswap(a, b);
  union { unsigned int u; float f; } pa, pb; pa.u = a; pb.u = b;
  return fmaxf(pa.f, pb.f);
}
DEV float xhalf_sum(float v) {
  union { float f; unsigned int u; } x; x.f = v;
  unsigned int a = x.u, b = x.u;
  permswap(a, b);
  union { unsigned int u; float f; } pa, pb; pa.u = a; pb.u = b;
  return pa.f + pb.f;
}

// ---------------- f32 -> bf16 convert (n multiple of 8) ----------------
__global__ __launch_bounds__(256) void k_cvt_bf16(const float* __restrict__ in,
                                                  unsigned short* __restrict__ out,
                                                  int n8) {
  int i = blockIdx.x * 256 + threadIdx.x;
  if (i >= n8) return;
  const f32x4* p = (const f32x4*)(in + (size_t)i * 8);
  f32x4 a = p[0], b = p[1];
  short8 o;
  o[0] = (short)f2bf(a[0]); o[1] = (short)f2bf(a[1]);
  o[2] = (short)f2bf(a[2]); o[3] = (short)f2bf(a[3]);
  o[4] = (short)f2bf(b[0]); o[5] = (short)f2bf(b[1]);
  o[6] = (short)f2bf(b[2]); o[7] = (short)f2bf(b[3]);
  *(short8*)(out + (size_t)i * 8) = o;
}

// 4 weight matrices in one launch (same size NDM*NDM)
__global__ __launch_bounds__(256) void k_cvt_w(const float* __restrict__ w0, const float* __restrict__ w1,
                                               const float* __restrict__ w2, const float* __restrict__ w3,
                                               unsigned short* __restrict__ o0, unsigned short* __restrict__ o1,
                                               unsigned short* __restrict__ o2, unsigned short* __restrict__ o3) {
  int i = blockIdx.x * 256 + threadIdx.x;  // per-matrix idx (x8 elems)
  int m = blockIdx.y;
  const float* in = (m == 0) ? w0 : (m == 1) ? w1 : (m == 2) ? w2 : w3;
  unsigned short* out = (m == 0) ? o0 : (m == 1) ? o1 : (m == 2) ? o2 : o3;
  const f32x4* p = (const f32x4*)(in + (size_t)i * 8);
  f32x4 a = p[0], b = p[1];
  short8 o;
  o[0] = (short)f2bf(a[0]); o[1] = (short)f2bf(a[1]);
  o[2] = (short)f2bf(a[2]); o[3] = (short)f2bf(a[3]);
  o[4] = (short)f2bf(b[0]); o[5] = (short)f2bf(b[1]);
  o[6] = (short)f2bf(b[2]); o[7] = (short)f2bf(b[3]);
  *(short8*)(out + (size_t)i * 8) = o;
}

// ---------------- GEMM: C[M][N] = A[M][K] @ B[N][K]^T + bias ----------------
template <int OUT_BF16>
__global__ __launch_bounds__(256) void k_gemm_bt(const unsigned short* __restrict__ A,
                                                 const unsigned short* __restrict__ Bw,
                                                 const float* __restrict__ bias,
                                                 void* __restrict__ Cout,
                                                 int M, int N, int K) {
  __shared__ unsigned short lA[128 * 32];
  __shared__ unsigned short lB[128 * 32];
  const int tid = threadIdx.x;
  const int lane = tid & 63;
  const int wave = tid >> 6;
  const int wr = (wave >> 1) * 64;
  const int wc = (wave & 1) * 64;
  const int lq = lane & 15;
  const int lk = (lane >> 4) * 8;

  // XCD-aware bijective swizzle (nwg = 512, divisible by 8)
  unsigned int nbx = gridDim.x;
  unsigned int bid = blockIdx.y * nbx + blockIdx.x;
  unsigned int cpx = (nbx * gridDim.y) >> 3;
  unsigned int swz = (bid & 7) * cpx + (bid >> 3);
  const int bn = swz % nbx, bm = swz / nbx;

  const unsigned short* Ab = A + (size_t)bm * 128 * K;
  const unsigned short* Bb = Bw + (size_t)bn * 128 * K;
  const int r0 = tid >> 2;
  const int c0 = (tid & 3) * 8;

  f32x4 acc[4][4] = {};

  for (int k0 = 0; k0 < K; k0 += 32) {
    __syncthreads();
    __builtin_amdgcn_global_load_lds(
        (const __attribute__((address_space(1))) void*)(Ab + (size_t)r0 * K + k0 + c0),
        (__attribute__((address_space(3))) void*)(lA + tid * 8), 16, 0, 0);
    __builtin_amdgcn_global_load_lds(
        (const __attribute__((address_space(1))) void*)(Ab + (size_t)(r0 + 64) * K + k0 + c0),
        (__attribute__((address_space(3))) void*)(lA + 2048 + tid * 8), 16, 0, 0);
    __builtin_amdgcn_global_load_lds(
        (const __attribute__((address_space(1))) void*)(Bb + (size_t)r0 * K + k0 + c0),
        (__attribute__((address_space(3))) void*)(lB + tid * 8), 16, 0, 0);
    __builtin_amdgcn_global_load_lds(
        (const __attribute__((address_space(1))) void*)(Bb + (size_t)(r0 + 64) * K + k0 + c0),
        (__attribute__((address_space(3))) void*)(lB + 2048 + tid * 8), 16, 0, 0);
    __syncthreads();

    short8 af[4], bf[4];
#pragma unroll
    for (int i = 0; i < 4; ++i) af[i] = *(const short8*)&lA[(wr + i * 16 + lq) * 32 + lk];
#pragma unroll
    for (int j = 0; j < 4; ++j) bf[j] = *(const short8*)&lB[(wc + j * 16 + lq) * 32 + lk];
#pragma unroll
    for (int i = 0; i < 4; ++i)
#pragma unroll
      for (int j = 0; j < 4; ++j)
        acc[i][j] = __builtin_amdgcn_mfma_f32_16x16x32_bf16(af[i], bf[j], acc[i][j], 0, 0, 0);
  }

  const int rowb = bm * 128 + wr + (lane >> 4) * 4;
  const int colb = bn * 128 + wc + lq;
#pragma unroll
  for (int i = 0; i < 4; ++i) {
#pragma unroll
    for (int j = 0; j < 4; ++j) {
      const int col = colb + j * 16;
      const float bs = bias[col];
#pragma unroll
      for (int r = 0; r < 4; ++r) {
        const size_t idx = (size_t)(rowb + i * 16 + r) * N + col;
        const float v = acc[i][j][r] + bs;
        if (OUT_BF16) ((unsigned short*)Cout)[idx] = f2bf(v);
        else          ((float*)Cout)[idx] = v;
      }
    }
  }
}

// ---------------- RoPE table ----------------
__global__ __launch_bounds__(256) void k_rope_table(float2* __restrict__ tab) {
  int i = blockIdx.x * 256 + threadIdx.x;  // NT*32
  int t = i >> 5, f = i & 31;
  float inv = powf(10000.0f, -(float)f / 32.0f);
  float ang = (float)t * inv;
  tab[i] = make_float2(cosf(ang), sinf(ang));
}

// ---------------- RoPE apply + head transpose: [B*T][DM] -> [B][H][T][DH] ----------------
template <int SCALE>
__global__ __launch_bounds__(256) void k_rope_apply(const unsigned short* __restrict__ in,
                                                    const float2* __restrict__ tab,
                                                    unsigned short* __restrict__ out) {
  int i = blockIdx.x * 256 + threadIdx.x;  // B*T*H threads
  int h = i & 15;
  int m = i >> 4;           // b*T + t
  int t = m & (NT - 1);
  int b = m >> 11;
  const unsigned short* src = in + (size_t)m * NDM + h * NDH;
  unsigned short* dst = out + (((size_t)(b * NH + h)) * NT + t) * NDH;
  const float2* tb = tab + (size_t)t * 32;
  const float qs = 0.125f * 1.44269504088896f;
#pragma unroll
  for (int c = 0; c < 8; ++c) {
    short8 v = *(const short8*)&src[c * 8];
    short8 o;
#pragma unroll
    for (int p = 0; p < 4; ++p) {
      float x0 = bf2f((unsigned short)v[2 * p]);
      float x1 = bf2f((unsigned short)v[2 * p + 1]);
      float2 cs = tb[c * 4 + p];
      float y0 = x0 * cs.x - x1 * cs.y;
      float y1 = x0 * cs.y + x1 * cs.x;
      if (SCALE) { y0 *= qs; y1 *= qs; }
      o[2 * p] = (short)f2bf(y0);
      o[2 * p + 1] = (short)f2bf(y1);
    }
    *(short8*)&dst[c * 8] = o;
  }
}

// ---------------- V transpose: [B*T][DM] -> Vt[B][H][DH][T] ----------------
__global__ __launch_bounds__(256) void k_v_transpose(const unsigned short* __restrict__ in,
                                                     unsigned short* __restrict__ out) {
  __shared__ unsigned short tile[64][64];
  const int bid = blockIdx.x;
  const int tt = bid & 31;
  const int h = (bid >> 5) & 15;
  const int b = bid >> 9;
  const int t0 = tt * 64;
  const int tid = threadIdx.x;
  {
    const int row = tid >> 3;
    const int cc = (tid & 7) * 8;
#pragma unroll
    for (int s = 0; s < 2; ++s) {
      const int t = row + s * 32;
      short8 v = *(const short8*)&in[((size_t)(b * NT) + t0 + t) * NDM + h * NDH + cc];
      *(short8*)&tile[t][cc] = v;
    }
  }
  __syncthreads();
  {
    const int d = tid >> 2;
    const int tq = tid & 3;
    unsigned short tmp[16];
#pragma unroll
    for (int j = 0; j < 16; ++j) tmp[j] = tile[tq * 16 + j][d];
    short8 o0, o1;
#pragma unroll
    for (int j = 0; j < 8; ++j) { o0[j] = (short)tmp[j]; o1[j] = (short)tmp[8 + j]; }
    const size_t base = (((size_t)(b * NH + h)) * NDH + d) * NT + t0 + tq * 16;
    *(short8*)&out[base] = o0;
    *(short8*)&out[base + 8] = o1;
  }
}

// ---------------- causal flash attention: 32x32 MFMA, in-register softmax ----------------
// grid: [B*H * 16]; 4 waves/block; each wave owns ONE 32-row q-tile (pair split across
// two blocks; adjacent block groups complementary -> balanced). bh grouped per XCD.
// Swapped QK^T; softmax in-register (log2 domain, defer-max THR=8); P redistribution
// and cross-half reductions via __builtin_amdgcn_permlane32_swap (VALU pipe, no LDS).
__global__ __launch_bounds__(256, 2) void k_attn(const unsigned short* __restrict__ Qh,
                                                 const unsigned short* __restrict__ Kh,
                                                 const unsigned short* __restrict__ Vt,
                                                 unsigned short* __restrict__ Ctx) {
  const int tid = threadIdx.x;
  const int wave = tid >> 6, lane = tid & 63;
  const int l31 = lane & 31, hi = lane >> 5;
  const int b0 = blockIdx.x;
  const int bh = (b0 & 7) * 8 + ((b0 >> 3) & 7);  // XCD-local bh grouping
  const int rem = b0 >> 6;                        // 0..15
  const int tt = rem & 1;
  const int pairIdx = (rem >> 1) * 4 + wave;      // 0..31
  const int b = bh >> 4, h = bh & 15;

  const unsigned short* K = Kh + (size_t)bh * NT * NDH;
  const unsigned short* V = Vt + (size_t)bh * NDH * NT;

  const int j = tt ? (63 - pairIdx) : pairIdx;  // 32-row tile index in [0,64)
  const int q0 = j * 32;
  const int nb = j + 1;  // number of 32-wide kv blocks

  // Q fragment (B-operand): lane holds Q[q0+l31][16s + 8hi + 0..7]
  const unsigned short* Qr = Qh + ((size_t)bh * NT + q0 + l31) * NDH + 8 * hi;
  short8 qf[4];
#pragma unroll
  for (int s = 0; s < 4; ++s) qf[s] = *(const short8*)&Qr[16 * s];

  f32x16 ot0 = {}, ot1 = {};
  float m_run = -1e30f, l_run = 0.0f;

  short8 kA[4], kB[4], vA[4], vB[4];
  {
    const unsigned short* Kr = K + (size_t)l31 * NDH + 8 * hi;
#pragma unroll
    for (int s = 0; s < 4; ++s) kA[s] = *(const short8*)&Kr[16 * s];
#pragma unroll
    for (int dt = 0; dt < 2; ++dt)
#pragma unroll
      for (int s = 0; s < 2; ++s)
        vA[dt * 2 + s] = *(const short8*)&V[(size_t)(dt * 32 + l31) * NT + 16 * s + 8 * hi];
  }

  auto body = [&](int kv0, int kv0n, short8 (&kc)[4], short8 (&vc)[4],
                  short8 (&kn)[4], short8 (&vn)[4]) {
    // QK^T: st[r] = S^T[k = kv0 + (r&3)+8*(r>>2)+4hi][q = q0+l31] (log2 domain)
    f32x16 st = {};
    __builtin_amdgcn_s_setprio(1);
#pragma unroll
    for (int s = 0; s < 4; ++s)
      st = __builtin_amdgcn_mfma_f32_32x32x16_bf16(kc[s], qf[s], st, 0, 0, 0);
    __builtin_amdgcn_s_setprio(0);
    // prefetch next kv block (K and V) into the other buffers
    {
      const unsigned short* Kr = K + (size_t)(kv0n + l31) * NDH + 8 * hi;
#pragma unroll
      for (int s = 0; s < 4; ++s) kn[s] = *(const short8*)&Kr[16 * s];
#pragma unroll
      for (int dt = 0; dt < 2; ++dt)
#pragma unroll
        for (int s = 0; s < 2; ++s)
          vn[dt * 2 + s] = *(const short8*)&V[(size_t)(dt * 32 + l31) * NT + kv0n + 16 * s + 8 * hi];
    }
    // causal mask (diagonal block only)
    if (kv0 + 32 > q0) {
      const int qg = q0 + l31;
#pragma unroll
      for (int r = 0; r < 16; ++r) {
        const int krow = kv0 + (r & 3) + 8 * (r >> 2) + 4 * hi;
        if (krow > qg) st[r] = -1e30f;
      }
    }
    // row max: tree (depth 4) + cross-half via permlane32_swap
    float mx;
    {
      float t0a = fmaxf(fmaxf(st[0], st[1]), fmaxf(st[2], st[3]));
      float t1a = fmaxf(fmaxf(st[4], st[5]), fmaxf(st[6], st[7]));
      float t2a = fmaxf(fmaxf(st[8], st[9]), fmaxf(st[10], st[11]));
      float t3a = fmaxf(fmaxf(st[12], st[13]), fmaxf(st[14], st[15]));
      mx = xhalf_max(fmaxf(fmaxf(t0a, t1a), fmaxf(t2a, t3a)));
    }
    // defer-max: only rescale when max grew by > 8 (P bounded by 2^8)
    if (!__all(mx - m_run <= 8.0f)) {
      const float m_new = fmaxf(m_run, mx);
      const float alpha = exp2f(m_run - m_new);
      l_run *= alpha;
      m_run = m_new;
#pragma unroll
      for (int r = 0; r < 16; ++r) { ot0[r] *= alpha; ot1[r] *= alpha; }
    }
    float pv[16];
#pragma unroll
    for (int r = 0; r < 16; ++r) pv[r] = exp2f(st[r] - m_run);
    {
      float s0 = (pv[0] + pv[1]) + (pv[2] + pv[3]);
      float s1 = (pv[4] + pv[5]) + (pv[6] + pv[7]);
      float s2 = (pv[8] + pv[9]) + (pv[10] + pv[11]);
      float s3 = (pv[12] + pv[13]) + (pv[14] + pv[15]);
      l_run += xhalf_sum((s0 + s1) + (s2 + s3));
    }
    // build PV B-fragments: lane needs P^T[16s + 8hi + jj][q=l31].
    // One permlane32_swap fills BOTH needed words (own-half + partner-half).
    short8 pf[2];
#pragma unroll
    for (int s = 0; s < 2; ++s) {
      const int o = s * 8;
      unsigned int w0 = pack2bf(pv[o + 0], pv[o + 1]);
      unsigned int w2 = pack2bf(pv[o + 4], pv[o + 5]);
      permswap(w0, w2);
      unsigned int w1 = pack2bf(pv[o + 2], pv[o + 3]);
      unsigned int w3 = pack2bf(pv[o + 6], pv[o + 7]);
      permswap(w1, w3);
      pf[s] = mkfrag(w0, w1, w2, w3);
    }
    // PV: Ot[d][q] += V^T * P^T
    __builtin_amdgcn_s_setprio(1);
    ot0 = __builtin_amdgcn_mfma_f32_32x32x16_bf16(vc[0], pf[0], ot0, 0, 0, 0);
    ot0 = __builtin_amdgcn_mfma_f32_32x32x16_bf16(vc[1], pf[1], ot0, 0, 0, 0);
    ot1 = __builtin_amdgcn_mfma_f32_32x32x16_bf16(vc[2], pf[0], ot1, 0, 0, 0);
    ot1 = __builtin_amdgcn_mfma_f32_32x32x16_bf16(vc[3], pf[1], ot1, 0, 0, 0);
    __builtin_amdgcn_s_setprio(0);
  };

  int kb = 0;
  while (kb < nb) {
    int kv0 = kb * 32;
    int kv0n = (kb + 1 < nb) ? kv0 + 32 : 0;
    body(kv0, kv0n, kA, vA, kB, vB);
    ++kb;
    if (kb >= nb) break;
    kv0 = kb * 32;
    kv0n = (kb + 1 < nb) ? kv0 + 32 : 0;
    body(kv0, kv0n, kB, vB, kA, vA);
    ++kb;
  }

  // epilogue: Ot[d][q] / l -> Ctx[b*T + q][h*64 + d]
  const float inv_l = 1.0f / l_run;
  unsigned short* dst = Ctx + ((size_t)(b * NT) + q0 + l31) * NDM + h * NDH;
#pragma unroll
  for (int dt = 0; dt < 2; ++dt) {
#pragma unroll
    for (int grp = 0; grp < 4; ++grp) {
      u16x4 w;
#pragma unroll
      for (int r = 0; r < 4; ++r) {
        const float v = (dt ? ot1[grp * 4 + r] : ot0[grp * 4 + r]) * inv_l;
        w[r] = f2bf(v);
      }
      *(u16x4*)&dst[dt * 32 + grp * 8 + 4 * hi] = w;
    }
  }
}

extern "C" void kernel_launch(void* const* d_in, const int* in_sizes, int n_in,
                              void* d_out, int out_size, void* d_ws, size_t ws_size,
                              hipStream_t stream) {
  const float* x  = (const float*)d_in[0];
  const float* Wq = (const float*)d_in[1];
  const float* bq = (const float*)d_in[2];
  const float* Wk = (const float*)d_in[3];
  const float* bk = (const float*)d_in[4];
  const float* Wv = (const float*)d_in[5];
  const float* bv = (const float*)d_in[6];
  const float* Wo = (const float*)d_in[7];
  const float* bo = (const float*)d_in[8];

  char* ws = (char*)d_ws;
  const size_t MB = 1024 * 1024;
  if (ws_size < 105 * MB) return;

  unsigned short* XB   = (unsigned short*)(ws + 0);        // 16MB; reused as VT
  unsigned short* WQB  = (unsigned short*)(ws + 16 * MB);
  unsigned short* WKB  = (unsigned short*)(ws + 18 * MB);
  unsigned short* WVB  = (unsigned short*)(ws + 20 * MB);
  unsigned short* WOB  = (unsigned short*)(ws + 22 * MB);
  unsigned short* QBUF = (unsigned short*)(ws + 24 * MB);  // 16MB; reused as CTX
  unsigned short* KBUF = (unsigned short*)(ws + 40 * MB);
  unsigned short* VBUF = (unsigned short*)(ws + 56 * MB);
  unsigned short* QH   = (unsigned short*)(ws + 72 * MB);
  unsigned short* KH   = (unsigned short*)(ws + 88 * MB);
  float2* TAB          = (float2*)(ws + 104 * MB);         // 512KB
  unsigned short* VT = XB;
  unsigned short* CTX = QBUF;

  // converts
  k_cvt_bf16<<<(NM * NDM / 8) / 256, 256, 0, stream>>>(x, XB, NM * NDM / 8);
  dim3 gw((NDM * NDM / 8) / 256, 4);
  k_cvt_w<<<gw, 256, 0, stream>>>(Wq, Wk, Wv, Wo, WQB, WKB, WVB, WOB);
  k_rope_table<<<(NT * 32) / 256, 256, 0, stream>>>(TAB);

  // QKV projections
  dim3 gg(NDM / 128, NM / 128);
  k_gemm_bt<1><<<gg, 256, 0, stream>>>(XB, WQB, bq, QBUF, NM, NDM, NDM);
  k_gemm_bt<1><<<gg, 256, 0, stream>>>(XB, WKB, bk, KBUF, NM, NDM, NDM);
  k_gemm_bt<1><<<gg, 256, 0, stream>>>(XB, WVB, bv, VBUF, NM, NDM, NDM);

  // rope + transposes
  k_rope_apply<1><<<(NB * NT * NH) / 256, 256, 0, stream>>>(QBUF, TAB, QH);
  k_rope_apply<0><<<(NB * NT * NH) / 256, 256, 0, stream>>>(KBUF, TAB, KH);
  k_v_transpose<<<NB * NH * (NT / 64), 256, 0, stream>>>(VBUF, VT);

  // attention (1024 blocks: 64 bh x 16; one 32-row q-tile per wave)
  k_attn<<<NB * NH * 16, 256, 0, stream>>>(QH, KH, VT, CTX);

  // output projection (f32 out)
  k_gemm_bt<0><<<gg, 256, 0, stream>>>(CTX, WOB, bo, d_out, NM, NDM, NDM);
}

// Round 6
// 270.867 us; speedup vs baseline: 1.1616x; 1.1616x over previous
//
#include <hip/hip_runtime.h>
#include <hip/hip_bf16.h>

#define DEV static __device__ __forceinline__

typedef __attribute__((ext_vector_type(4))) float f32x4;
typedef __attribute__((ext_vector_type(16))) float f32x16;
typedef __attribute__((ext_vector_type(8))) short short8;
typedef __attribute__((ext_vector_type(4))) unsigned short u16x4;
typedef __attribute__((ext_vector_type(4))) unsigned int u32x4;

#define NB 4
#define NT 2048
#define NDM 1024
#define NH 16
#define NDH 64
#define NM (NB * NT)  // 8192 rows

DEV float bf2f(unsigned short u) {
  union { unsigned int i; float f; } x;
  x.i = ((unsigned int)u) << 16;
  return x.f;
}
DEV unsigned short f2bf(float f) {
  __hip_bfloat16 h = __float2bfloat16(f);
  return *reinterpret_cast<unsigned short*>(&h);
}
DEV unsigned int pack2bf(float lo, float hi) {
  return ((unsigned int)f2bf(hi) << 16) | (unsigned int)f2bf(lo);
}
DEV short8 mkfrag(unsigned int w0, unsigned int w1, unsigned int w2, unsigned int w3) {
  union { u32x4 u; short8 s; } x;
  x.u[0] = w0; x.u[1] = w1; x.u[2] = w2; x.u[3] = w3;
  return x.s;
}
// exchange lane i <-> lane i^32 for both values (builtin returns BOTH results ->
// compiler must materialize two distinct regs; inline-asm "+v","+v" self-swapped).
DEV void permswap(unsigned int& a, unsigned int& b) {
  auto r = __builtin_amdgcn_permlane32_swap(a, b, false, false);
  a = r[0]; b = r[1];
}
DEV float xhalf_max(float v) {
  union { float f; unsigned int u; } x; x.f = v;
  unsigned int a = x.u, b = x.u;
  permswap(a, b);
  union { unsigned int u; float f; } pa, pb; pa.u = a; pb.u = b;
  return fmaxf(pa.f, pb.f);
}
DEV float xhalf_sum(float v) {
  union { float f; unsigned int u; } x; x.f = v;
  unsigned int a = x.u, b = x.u;
  permswap(a, b);
  union { unsigned int u; float f; } pa, pb; pa.u = a; pb.u = b;
  return pa.f + pb.f;
}

// ---------------- f32 -> bf16 convert ----------------
__global__ __launch_bounds__(256) void k_cvt_bf16(const float* __restrict__ in,
                                                  unsigned short* __restrict__ out,
                                                  int n8) {
  int i = blockIdx.x * 256 + threadIdx.x;
  if (i >= n8) return;
  const f32x4* p = (const f32x4*)(in + (size_t)i * 8);
  f32x4 a = p[0], b = p[1];
  short8 o;
  o[0] = (short)f2bf(a[0]); o[1] = (short)f2bf(a[1]);
  o[2] = (short)f2bf(a[2]); o[3] = (short)f2bf(a[3]);
  o[4] = (short)f2bf(b[0]); o[5] = (short)f2bf(b[1]);
  o[6] = (short)f2bf(b[2]); o[7] = (short)f2bf(b[3]);
  *(short8*)(out + (size_t)i * 8) = o;
}

// 4 weight matrices in one launch
__global__ __launch_bounds__(256) void k_cvt_w(const float* __restrict__ w0, const float* __restrict__ w1,
                                               const float* __restrict__ w2, const float* __restrict__ w3,
                                               unsigned short* __restrict__ o0, unsigned short* __restrict__ o1,
                                               unsigned short* __restrict__ o2, unsigned short* __restrict__ o3) {
  int i = blockIdx.x * 256 + threadIdx.x;
  int m = blockIdx.y;
  const float* in = (m == 0) ? w0 : (m == 1) ? w1 : (m == 2) ? w2 : w3;
  unsigned short* out = (m == 0) ? o0 : (m == 1) ? o1 : (m == 2) ? o2 : o3;
  const f32x4* p = (const f32x4*)(in + (size_t)i * 8);
  f32x4 a = p[0], b = p[1];
  short8 o;
  o[0] = (short)f2bf(a[0]); o[1] = (short)f2bf(a[1]);
  o[2] = (short)f2bf(a[2]); o[3] = (short)f2bf(a[3]);
  o[4] = (short)f2bf(b[0]); o[5] = (short)f2bf(b[1]);
  o[6] = (short)f2bf(b[2]); o[7] = (short)f2bf(b[3]);
  *(short8*)(out + (size_t)i * 8) = o;
}

// ---------------- fused QKV GEMM: C{q,k,v}[M][1024] = A @ [Wq|Wk|Wv]^T + b ----------------
// N_total = 3072; weight rows contiguous in ws (WQB,WKB,WVB adjacent).
// Output/bias buffer selected per block: which = bn>>3 (128-col tiles, 1024%128==0).
__global__ __launch_bounds__(256) void k_gemm_qkv(const unsigned short* __restrict__ A,
                                                  const unsigned short* __restrict__ Bw,
                                                  const float* __restrict__ bq,
                                                  const float* __restrict__ bk,
                                                  const float* __restrict__ bv,
                                                  unsigned short* __restrict__ Cq,
                                                  unsigned short* __restrict__ Ck,
                                                  unsigned short* __restrict__ Cv) {
  __shared__ unsigned short lA[128 * 32];
  __shared__ unsigned short lB[128 * 32];
  const int K = NDM;
  const int tid = threadIdx.x;
  const int lane = tid & 63;
  const int wave = tid >> 6;
  const int wr = (wave >> 1) * 64;
  const int wc = (wave & 1) * 64;
  const int lq = lane & 15;
  const int lk = (lane >> 4) * 8;

  // XCD-aware bijective swizzle (nwg = 1536, divisible by 8)
  unsigned int nbx = gridDim.x;  // 24
  unsigned int bid = blockIdx.y * nbx + blockIdx.x;
  unsigned int cpx = (nbx * gridDim.y) >> 3;
  unsigned int swz = (bid & 7) * cpx + (bid >> 3);
  const int bn = swz % nbx, bm = swz / nbx;

  const unsigned short* Ab = A + (size_t)bm * 128 * K;
  const unsigned short* Bb = Bw + (size_t)bn * 128 * K;
  const int r0 = tid >> 2;
  const int c0 = (tid & 3) * 8;

  f32x4 acc[4][4] = {};

  for (int k0 = 0; k0 < K; k0 += 32) {
    __syncthreads();
    __builtin_amdgcn_global_load_lds(
        (const __attribute__((address_space(1))) void*)(Ab + (size_t)r0 * K + k0 + c0),
        (__attribute__((address_space(3))) void*)(lA + tid * 8), 16, 0, 0);
    __builtin_amdgcn_global_load_lds(
        (const __attribute__((address_space(1))) void*)(Ab + (size_t)(r0 + 64) * K + k0 + c0),
        (__attribute__((address_space(3))) void*)(lA + 2048 + tid * 8), 16, 0, 0);
    __builtin_amdgcn_global_load_lds(
        (const __attribute__((address_space(1))) void*)(Bb + (size_t)r0 * K + k0 + c0),
        (__attribute__((address_space(3))) void*)(lB + tid * 8), 16, 0, 0);
    __builtin_amdgcn_global_load_lds(
        (const __attribute__((address_space(1))) void*)(Bb + (size_t)(r0 + 64) * K + k0 + c0),
        (__attribute__((address_space(3))) void*)(lB + 2048 + tid * 8), 16, 0, 0);
    __syncthreads();

    short8 af[4], bf[4];
#pragma unroll
    for (int i = 0; i < 4; ++i) af[i] = *(const short8*)&lA[(wr + i * 16 + lq) * 32 + lk];
#pragma unroll
    for (int j = 0; j < 4; ++j) bf[j] = *(const short8*)&lB[(wc + j * 16 + lq) * 32 + lk];
#pragma unroll
    for (int i = 0; i < 4; ++i)
#pragma unroll
      for (int j = 0; j < 4; ++j)
        acc[i][j] = __builtin_amdgcn_mfma_f32_16x16x32_bf16(af[i], bf[j], acc[i][j], 0, 0, 0);
  }

  const int which = bn >> 3;  // 0:q 1:k 2:v (uniform per block)
  unsigned short* Cout = (which == 0) ? Cq : (which == 1) ? Ck : Cv;
  const float* bias = (which == 0) ? bq : (which == 1) ? bk : bv;
  const int nloc = (bn & 7) * 128;  // col offset within the selected 1024-wide output

  const int rowb = bm * 128 + wr + (lane >> 4) * 4;
  const int colb = nloc + wc + lq;
#pragma unroll
  for (int i = 0; i < 4; ++i) {
#pragma unroll
    for (int j = 0; j < 4; ++j) {
      const int col = colb + j * 16;
      const float bs = bias[col];
#pragma unroll
      for (int r = 0; r < 4; ++r) {
        const size_t idx = (size_t)(rowb + i * 16 + r) * NDM + col;
        const float v = acc[i][j][r] + bs;
        Cout[idx] = f2bf(v);
      }
    }
  }
}

// ---------------- output GEMM: C[M][N] = A[M][K] @ B[N][K]^T + bias (f32 out) ----------------
__global__ __launch_bounds__(256) void k_gemm_bt(const unsigned short* __restrict__ A,
                                                 const unsigned short* __restrict__ Bw,
                                                 const float* __restrict__ bias,
                                                 float* __restrict__ Cout,
                                                 int M, int N, int K) {
  __shared__ unsigned short lA[128 * 32];
  __shared__ unsigned short lB[128 * 32];
  const int tid = threadIdx.x;
  const int lane = tid & 63;
  const int wave = tid >> 6;
  const int wr = (wave >> 1) * 64;
  const int wc = (wave & 1) * 64;
  const int lq = lane & 15;
  const int lk = (lane >> 4) * 8;

  unsigned int nbx = gridDim.x;
  unsigned int bid = blockIdx.y * nbx + blockIdx.x;
  unsigned int cpx = (nbx * gridDim.y) >> 3;
  unsigned int swz = (bid & 7) * cpx + (bid >> 3);
  const int bn = swz % nbx, bm = swz / nbx;

  const unsigned short* Ab = A + (size_t)bm * 128 * K;
  const unsigned short* Bb = Bw + (size_t)bn * 128 * K;
  const int r0 = tid >> 2;
  const int c0 = (tid & 3) * 8;

  f32x4 acc[4][4] = {};

  for (int k0 = 0; k0 < K; k0 += 32) {
    __syncthreads();
    __builtin_amdgcn_global_load_lds(
        (const __attribute__((address_space(1))) void*)(Ab + (size_t)r0 * K + k0 + c0),
        (__attribute__((address_space(3))) void*)(lA + tid * 8), 16, 0, 0);
    __builtin_amdgcn_global_load_lds(
        (const __attribute__((address_space(1))) void*)(Ab + (size_t)(r0 + 64) * K + k0 + c0),
        (__attribute__((address_space(3))) void*)(lA + 2048 + tid * 8), 16, 0, 0);
    __builtin_amdgcn_global_load_lds(
        (const __attribute__((address_space(1))) void*)(Bb + (size_t)r0 * K + k0 + c0),
        (__attribute__((address_space(3))) void*)(lB + tid * 8), 16, 0, 0);
    __builtin_amdgcn_global_load_lds(
        (const __attribute__((address_space(1))) void*)(Bb + (size_t)(r0 + 64) * K + k0 + c0),
        (__attribute__((address_space(3))) void*)(lB + 2048 + tid * 8), 16, 0, 0);
    __syncthreads();

    short8 af[4], bf[4];
#pragma unroll
    for (int i = 0; i < 4; ++i) af[i] = *(const short8*)&lA[(wr + i * 16 + lq) * 32 + lk];
#pragma unroll
    for (int j = 0; j < 4; ++j) bf[j] = *(const short8*)&lB[(wc + j * 16 + lq) * 32 + lk];
#pragma unroll
    for (int i = 0; i < 4; ++i)
#pragma unroll
      for (int j = 0; j < 4; ++j)
        acc[i][j] = __builtin_amdgcn_mfma_f32_16x16x32_bf16(af[i], bf[j], acc[i][j], 0, 0, 0);
  }

  const int rowb = bm * 128 + wr + (lane >> 4) * 4;
  const int colb = bn * 128 + wc + lq;
#pragma unroll
  for (int i = 0; i < 4; ++i) {
#pragma unroll
    for (int j = 0; j < 4; ++j) {
      const int col = colb + j * 16;
      const float bs = bias[col];
#pragma unroll
      for (int r = 0; r < 4; ++r) {
        const size_t idx = (size_t)(rowb + i * 16 + r) * N + col;
        Cout[idx] = acc[i][j][r] + bs;
      }
    }
  }
}

// ---------------- RoPE table ----------------
__global__ __launch_bounds__(256) void k_rope_table(float2* __restrict__ tab) {
  int i = blockIdx.x * 256 + threadIdx.x;  // NT*32
  int t = i >> 5, f = i & 31;
  float inv = powf(10000.0f, -(float)f / 32.0f);
  float ang = (float)t * inv;
  tab[i] = make_float2(cosf(ang), sinf(ang));
}

// ---------------- RoPE apply + head transpose ----------------
template <int SCALE>
__global__ __launch_bounds__(256) void k_rope_apply(const unsigned short* __restrict__ in,
                                                    const float2* __restrict__ tab,
                                                    unsigned short* __restrict__ out) {
  int i = blockIdx.x * 256 + threadIdx.x;  // B*T*H threads
  int h = i & 15;
  int m = i >> 4;
  int t = m & (NT - 1);
  int b = m >> 11;
  const unsigned short* src = in + (size_t)m * NDM + h * NDH;
  unsigned short* dst = out + (((size_t)(b * NH + h)) * NT + t) * NDH;
  const float2* tb = tab + (size_t)t * 32;
  const float qs = 0.125f * 1.44269504088896f;
#pragma unroll
  for (int c = 0; c < 8; ++c) {
    short8 v = *(const short8*)&src[c * 8];
    short8 o;
#pragma unroll
    for (int p = 0; p < 4; ++p) {
      float x0 = bf2f((unsigned short)v[2 * p]);
      float x1 = bf2f((unsigned short)v[2 * p + 1]);
      float2 cs = tb[c * 4 + p];
      float y0 = x0 * cs.x - x1 * cs.y;
      float y1 = x0 * cs.y + x1 * cs.x;
      if (SCALE) { y0 *= qs; y1 *= qs; }
      o[2 * p] = (short)f2bf(y0);
      o[2 * p + 1] = (short)f2bf(y1);
    }
    *(short8*)&dst[c * 8] = o;
  }
}

// ---------------- V transpose: [B*T][DM] -> Vt[B][H][DH][T] ----------------
__global__ __launch_bounds__(256) void k_v_transpose(const unsigned short* __restrict__ in,
                                                     unsigned short* __restrict__ out) {
  __shared__ unsigned short tile[64][64];
  const int bid = blockIdx.x;
  const int tt = bid & 31;
  const int h = (bid >> 5) & 15;
  const int b = bid >> 9;
  const int t0 = tt * 64;
  const int tid = threadIdx.x;
  {
    const int row = tid >> 3;
    const int cc = (tid & 7) * 8;
#pragma unroll
    for (int s = 0; s < 2; ++s) {
      const int t = row + s * 32;
      short8 v = *(const short8*)&in[((size_t)(b * NT) + t0 + t) * NDM + h * NDH + cc];
      *(short8*)&tile[t][cc] = v;
    }
  }
  __syncthreads();
  {
    const int d = tid >> 2;
    const int tq = tid & 3;
    unsigned short tmp[16];
#pragma unroll
    for (int j = 0; j < 16; ++j) tmp[j] = tile[tq * 16 + j][d];
    short8 o0, o1;
#pragma unroll
    for (int j = 0; j < 8; ++j) { o0[j] = (short)tmp[j]; o1[j] = (short)tmp[8 + j]; }
    const size_t base = (((size_t)(b * NH + h)) * NDH + d) * NT + t0 + tq * 16;
    *(short8*)&out[base] = o0;
    *(short8*)&out[base + 8] = o1;
  }
}

// ---------------- causal flash attention: software-pipelined ----------------
// grid: [B*H * 8]; 4 waves/block; wave handles 32-row q-tiles pairIdx AND 63-pairIdx
// (uniform 65 kv-units -> balanced). bh grouped per XCD.
// Pipeline per iter: softmax(k) -> QK(k+1) -> PV(k). In-order MFMA pipe => QK(k+1)
// completes before PV(k), so next softmax VALU overlaps PV MFMA execution.
// K/V triple-buffered in registers (static names); loads issued at iter start.
// Causal mask needed only at the final (diagonal) block -> out of the hot loop.
__global__ __launch_bounds__(256, 2) void k_attn(const unsigned short* __restrict__ Qh,
                                                 const unsigned short* __restrict__ Kh,
                                                 const unsigned short* __restrict__ Vt,
                                                 unsigned short* __restrict__ Ctx) {
  const int tid = threadIdx.x;
  const int wave = tid >> 6, lane = tid & 63;
  const int l31 = lane & 31, hi = lane >> 5;
  const int b0 = blockIdx.x;
  const int bh = (b0 & 7) * 8 + ((b0 >> 3) & 7);  // XCD-local bh grouping
  const int pairIdx = (b0 >> 6) * 4 + wave;       // 0..31
  const int b = bh >> 4, h = bh & 15;

  const unsigned short* K = Kh + (size_t)bh * NT * NDH;
  const unsigned short* V = Vt + (size_t)bh * NDH * NT;

  for (int tt = 0; tt < 2; ++tt) {
    const int j = tt ? (63 - pairIdx) : pairIdx;
    const int q0 = j * 32;
    const int nb = j + 1;  // 32-wide kv blocks

    const unsigned short* Qr = Qh + ((size_t)bh * NT + q0 + l31) * NDH + 8 * hi;
    short8 qf[4];
#pragma unroll
    for (int s = 0; s < 4; ++s) qf[s] = *(const short8*)&Qr[16 * s];

    f32x16 ot0 = {}, ot1 = {};
    float m_run = -1e30f, l_run = 0.0f;

    short8 kA[4], vA[4], kB[4], vB[4], kC[4], vC[4];

    auto loadKV = [&](int kidx, short8 (&kd)[4], short8 (&vd)[4]) {
      const int kv0 = (kidx < nb ? kidx : nb - 1) * 32;
      const unsigned short* Kr = K + (size_t)(kv0 + l31) * NDH + 8 * hi;
#pragma unroll
      for (int s = 0; s < 4; ++s) kd[s] = *(const short8*)&Kr[16 * s];
#pragma unroll
      for (int dt = 0; dt < 2; ++dt)
#pragma unroll
        for (int s = 0; s < 2; ++s)
          vd[dt * 2 + s] = *(const short8*)&V[(size_t)(dt * 32 + l31) * NT + kv0 + 16 * s + 8 * hi];
    };

    // softmax on st (block kidx already in st); produces pf; updates m_run/l_run/ot scale
    auto softmax = [&](f32x16& st, short8 (&pf)[2], bool diag) {
      if (diag) {
        const int qg = q0 + l31;
        const int kv0 = (nb - 1) * 32;
#pragma unroll
        for (int r = 0; r < 16; ++r) {
          const int krow = kv0 + (r & 3) + 8 * (r >> 2) + 4 * hi;
          if (krow > qg) st[r] = -1e30f;
        }
      }
      float t0a = fmaxf(fmaxf(st[0], st[1]), fmaxf(st[2], st[3]));
      float t1a = fmaxf(fmaxf(st[4], st[5]), fmaxf(st[6], st[7]));
      float t2a = fmaxf(fmaxf(st[8], st[9]), fmaxf(st[10], st[11]));
      float t3a = fmaxf(fmaxf(st[12], st[13]), fmaxf(st[14], st[15]));
      float mx = xhalf_max(fmaxf(fmaxf(t0a, t1a), fmaxf(t2a, t3a)));
      if (!__all(mx - m_run <= 8.0f)) {  // defer-max (log2 domain)
        const float m_new = fmaxf(m_run, mx);
        const float alpha = exp2f(m_run - m_new);
        l_run *= alpha;
        m_run = m_new;
#pragma unroll
        for (int r = 0; r < 16; ++r) { ot0[r] *= alpha; ot1[r] *= alpha; }
      }
      float pv[16];
#pragma unroll
      for (int r = 0; r < 16; ++r) pv[r] = exp2f(st[r] - m_run);
      {
        float s0 = (pv[0] + pv[1]) + (pv[2] + pv[3]);
        float s1 = (pv[4] + pv[5]) + (pv[6] + pv[7]);
        float s2 = (pv[8] + pv[9]) + (pv[10] + pv[11]);
        float s3 = (pv[12] + pv[13]) + (pv[14] + pv[15]);
        l_run += xhalf_sum((s0 + s1) + (s2 + s3));
      }
#pragma unroll
      for (int s = 0; s < 2; ++s) {
        const int o = s * 8;
        unsigned int w0 = pack2bf(pv[o + 0], pv[o + 1]);
        unsigned int w2 = pack2bf(pv[o + 4], pv[o + 5]);
        permswap(w0, w2);
        unsigned int w1 = pack2bf(pv[o + 2], pv[o + 3]);
        unsigned int w3 = pack2bf(pv[o + 6], pv[o + 7]);
        permswap(w1, w3);
        pf[s] = mkfrag(w0, w1, w2, w3);
      }
    };

    auto qk = [&](short8 (&kc)[4]) -> f32x16 {
      f32x16 s = {};
#pragma unroll
      for (int ss = 0; ss < 4; ++ss)
        s = __builtin_amdgcn_mfma_f32_32x32x16_bf16(kc[ss], qf[ss], s, 0, 0, 0);
      return s;
    };
    auto pvacc = [&](short8 (&vc)[4], short8 (&pf)[2]) {
      ot0 = __builtin_amdgcn_mfma_f32_32x32x16_bf16(vc[0], pf[0], ot0, 0, 0, 0);
      ot0 = __builtin_amdgcn_mfma_f32_32x32x16_bf16(vc[1], pf[1], ot0, 0, 0, 0);
      ot1 = __builtin_amdgcn_mfma_f32_32x32x16_bf16(vc[2], pf[0], ot1, 0, 0, 0);
      ot1 = __builtin_amdgcn_mfma_f32_32x32x16_bf16(vc[3], pf[1], ot1, 0, 0, 0);
    };

    // pipelined iteration: loads(k+2) -> softmax(k) -> QK(k+1) -> PV(k)
    auto iter = [&](f32x16& st, short8 (&vcur)[4], short8 (&knext)[4],
                    short8 (&kload)[4], short8 (&vload)[4], int kidx) {
      loadKV(kidx + 2, kload, vload);
      short8 pf[2];
      softmax(st, pf, false);
      f32x16 stn = qk(knext);
      pvacc(vcur, pf);
      st = stn;
    };
    auto fin = [&](f32x16& st, short8 (&vcur)[4]) {
      short8 pf[2];
      softmax(st, pf, true);
      pvacc(vcur, pf);
    };

    // prologue
    loadKV(0, kA, vA);
    loadKV(nb > 1 ? 1 : 0, kB, vB);
    f32x16 st = qk(kA);

    int k = 0;
    while (k + 3 <= nb - 1) {  // keeps k % 3 == 0
      iter(st, vA, kB, kC, vC, k);
      iter(st, vB, kC, kA, vA, k + 1);
      iter(st, vC, kA, kB, vB, k + 2);
      k += 3;
    }
    const int rem = nb - 1 - k;  // 0, 1, or 2
    if (rem == 0) {
      fin(st, vA);
    } else if (rem == 1) {
      iter(st, vA, kB, kC, vC, k);
      fin(st, vB);
    } else {
      iter(st, vA, kB, kC, vC, k);
      iter(st, vB, kC, kA, vA, k + 1);
      fin(st, vC);
    }

    // epilogue
    const float inv_l = 1.0f / l_run;
    unsigned short* dst = Ctx + ((size_t)(b * NT) + q0 + l31) * NDM + h * NDH;
#pragma unroll
    for (int dt = 0; dt < 2; ++dt) {
#pragma unroll
      for (int grp = 0; grp < 4; ++grp) {
        u16x4 w;
#pragma unroll
        for (int r = 0; r < 4; ++r) {
          const float v = (dt ? ot1[grp * 4 + r] : ot0[grp * 4 + r]) * inv_l;
          w[r] = f2bf(v);
        }
        *(u16x4*)&dst[dt * 32 + grp * 8 + 4 * hi] = w;
      }
    }
  }
}

extern "C" void kernel_launch(void* const* d_in, const int* in_sizes, int n_in,
                              void* d_out, int out_size, void* d_ws, size_t ws_size,
                              hipStream_t stream) {
  const float* x  = (const float*)d_in[0];
  const float* Wq = (const float*)d_in[1];
  const float* bq = (const float*)d_in[2];
  const float* Wk = (const float*)d_in[3];
  const float* bk = (const float*)d_in[4];
  const float* Wv = (const float*)d_in[5];
  const float* bv = (const float*)d_in[6];
  const float* Wo = (const float*)d_in[7];
  const float* bo = (const float*)d_in[8];

  char* ws = (char*)d_ws;
  const size_t MB = 1024 * 1024;
  if (ws_size < 105 * MB) return;

  unsigned short* XB   = (unsigned short*)(ws + 0);        // 16MB; reused as VT
  unsigned short* WQB  = (unsigned short*)(ws + 16 * MB);  // WQB|WKB|WVB contiguous
  unsigned short* WKB  = (unsigned short*)(ws + 18 * MB);
  unsigned short* WVB  = (unsigned short*)(ws + 20 * MB);
  unsigned short* WOB  = (unsigned short*)(ws + 22 * MB);
  unsigned short* QBUF = (unsigned short*)(ws + 24 * MB);  // 16MB; reused as CTX
  unsigned short* KBUF = (unsigned short*)(ws + 40 * MB);
  unsigned short* VBUF = (unsigned short*)(ws + 56 * MB);
  unsigned short* QH   = (unsigned short*)(ws + 72 * MB);
  unsigned short* KH   = (unsigned short*)(ws + 88 * MB);
  float2* TAB          = (float2*)(ws + 104 * MB);         // 512KB
  unsigned short* VT = XB;
  unsigned short* CTX = QBUF;

  // converts
  k_cvt_bf16<<<(NM * NDM / 8) / 256, 256, 0, stream>>>(x, XB, NM * NDM / 8);
  dim3 gw((NDM * NDM / 8) / 256, 4);
  k_cvt_w<<<gw, 256, 0, stream>>>(Wq, Wk, Wv, Wo, WQB, WKB, WVB, WOB);
  k_rope_table<<<(NT * 32) / 256, 256, 0, stream>>>(TAB);

  // fused QKV projection (N=3072): A read once
  dim3 gq(3 * NDM / 128, NM / 128);
  k_gemm_qkv<<<gq, 256, 0, stream>>>(XB, WQB, bq, bk, bv, QBUF, KBUF, VBUF);

  // rope + transposes
  k_rope_apply<1><<<(NB * NT * NH) / 256, 256, 0, stream>>>(QBUF, TAB, QH);
  k_rope_apply<0><<<(NB * NT * NH) / 256, 256, 0, stream>>>(KBUF, TAB, KH);
  k_v_transpose<<<NB * NH * (NT / 64), 256, 0, stream>>>(VBUF, VT);

  // attention (512 blocks: 64 bh x 8; paired tiles -> uniform 65 units/wave)
  k_attn<<<NB * NH * 8, 256, 0, stream>>>(QH, KH, VT, CTX);

  // output projection (f32 out)
  dim3 go(NDM / 128, NM / 128);
  k_gemm_bt<<<go, 256, 0, stream>>>(CTX, WOB, bo, (float*)d_out, NM, NDM, NDM);
}